// Round 8
// baseline (44.600 us; speedup 1.0000x reference)
//
#include <hip/hip_runtime.h>

#define THREADS 256
#define BLOCKS 2048
#define UNROLL 16

// Each block owns a contiguous 512 KiB chunk; 16 independent dwordx4 loads in
// flight per lane (256 B/lane), spaced 4 KiB apart within the chunk, 16
// independent accumulators.
__global__ __launch_bounds__(THREADS) void sum_stage1(
    const float4* __restrict__ x, float* __restrict__ partials, int n4) {
    const int per_block = n4 / BLOCKS;            // 8192 float4 = 512 KiB
    const int base = blockIdx.x * per_block;
    const int iters = per_block / (UNROLL * THREADS);  // 2

    float s[UNROLL];
    #pragma unroll
    for (int k = 0; k < UNROLL; ++k) s[k] = 0.f;

    int i = base + threadIdx.x;
    for (int g = 0; g < iters; ++g) {
        float4 v[UNROLL];
        #pragma unroll
        for (int k = 0; k < UNROLL; ++k) v[k] = x[i + k * THREADS];
        i += UNROLL * THREADS;
        #pragma unroll
        for (int k = 0; k < UNROLL; ++k)
            s[k] += (v[k].x + v[k].y) + (v[k].z + v[k].w);
    }
    // tail (empty for 64Mi elements; kept for generality)
    for (int j = base + iters * UNROLL * THREADS + threadIdx.x;
         j < base + per_block; j += THREADS) {
        float4 a = x[j];
        s[0] += (a.x + a.y) + (a.z + a.w);
    }

    float sum = 0.f;
    #pragma unroll
    for (int k = 0; k < UNROLL; ++k) sum += s[k];

    #pragma unroll
    for (int off = 32; off > 0; off >>= 1)
        sum += __shfl_down(sum, off, 64);
    __shared__ float lds[THREADS / 64];
    const int lane = threadIdx.x & 63;
    const int wave = threadIdx.x >> 6;
    if (lane == 0) lds[wave] = sum;
    __syncthreads();
    if (threadIdx.x == 0) {
        float t = 0.f;
        #pragma unroll
        for (int w = 0; w < THREADS / 64; ++w) t += lds[w];
        partials[blockIdx.x] = t;
    }
}

#define S2_THREADS 1024

__global__ __launch_bounds__(S2_THREADS) void sum_stage2(
    const float* __restrict__ partials, float* __restrict__ out, int n) {
    float s = 0.f;
    for (int i = threadIdx.x; i < n; i += S2_THREADS) s += partials[i];
    #pragma unroll
    for (int off = 32; off > 0; off >>= 1)
        s += __shfl_down(s, off, 64);
    __shared__ float lds[S2_THREADS / 64];
    const int lane = threadIdx.x & 63;
    const int wave = threadIdx.x >> 6;
    if (lane == 0) lds[wave] = s;
    __syncthreads();
    if (threadIdx.x == 0) {
        float t = 0.f;
        #pragma unroll
        for (int w = 0; w < S2_THREADS / 64; ++w) t += lds[w];
        out[0] = t;
    }
}

extern "C" void kernel_launch(void* const* d_in, const int* in_sizes, int n_in,
                              void* d_out, int out_size, void* d_ws, size_t ws_size,
                              hipStream_t stream) {
    const float* x = (const float*)d_in[0];
    float* out = (float*)d_out;
    float* partials = (float*)d_ws;   // BLOCKS floats = 8 KiB scratch

    const int n = in_sizes[0];        // 64*1024*1024
    const int n4 = n / 4;

    sum_stage1<<<BLOCKS, THREADS, 0, stream>>>((const float4*)x, partials, n4);
    sum_stage2<<<1, S2_THREADS, 0, stream>>>(partials, out, BLOCKS);
}